// Round 1
// baseline (132.054 us; speedup 1.0000x reference)
//
#include <hip/hip_runtime.h>
#include <hip/hip_bf16.h>

// GAT: out = softmax(mask(lrelu(w1 + w2^T), adj)) @ (x@W) + bias
// Strategy: adj (268 MB int32) is the only O(N^2) input -> stream it once,
// build masked-exp P tiles in registers, bf16 MFMA P@Wh, split columns 8-way
// with fp32 partial (numerator, Z) buffers, tiny final reduce kernel.

#define NN   8192
#define INF  256
#define OUTF 64
#define TILE1 32   // rows per block in k1
#define BM    64   // rows per block in k2
#define C0   1.0000900040501013f   // expf(9e-5)

typedef __bf16 bf16x8 __attribute__((ext_vector_type(8)));
typedef float  f32x4  __attribute__((ext_vector_type(4)));

__device__ __forceinline__ unsigned short f32_to_bf16(float f) {
    unsigned int u = __float_as_uint(f);
    u += 0x7FFFu + ((u >> 16) & 1u);   // round-to-nearest-even (finite values)
    return (unsigned short)(u >> 16);
}

// k1: Wh = x @ W; w1 = Wh@a1, w2 = Wh@a2; WhT = bf16(Wh)^T  [64][8192]
__global__ __launch_bounds__(256) void k1_proj(
    const float* __restrict__ x, const float* __restrict__ W,
    const float* __restrict__ alpha,
    unsigned short* __restrict__ WhT,
    float* __restrict__ w1, float* __restrict__ w2)
{
    __shared__ float xs[TILE1 * INF];    // 32 KB
    __shared__ float shwh[TILE1 * 65];   // padded for transpose reads
    const int tid = threadIdx.x;
    const int i0 = blockIdx.x * TILE1;

    // stage x rows (coalesced float4)
    const float4* xsrc = (const float4*)(x + (size_t)i0 * INF);
    float4* xdst = (float4*)xs;
#pragma unroll
    for (int it = 0; it < (TILE1 * INF / 4) / 256; ++it)
        xdst[tid + it * 256] = xsrc[tid + it * 256];
    __syncthreads();

    const int wave = tid >> 6, lane = tid & 63;
    const float a1 = alpha[lane], a2 = alpha[OUTF + lane];
    const int ilbase = wave * 8;

    float acc[8] = {};
#pragma unroll 4
    for (int k = 0; k < INF; ++k) {
        float wk = W[k * OUTF + lane];   // coalesced, L1/L2-resident
#pragma unroll
        for (int rr = 0; rr < 8; ++rr)
            acc[rr] = fmaf(xs[(ilbase + rr) * INF + k], wk, acc[rr]); // LDS broadcast
    }

#pragma unroll
    for (int rr = 0; rr < 8; ++rr) {
        const int il = ilbase + rr;
        const int i  = i0 + il;
        float a = acc[rr];
        float v1 = a * a1, v2 = a * a2;
#pragma unroll
        for (int off = 32; off > 0; off >>= 1) {
            v1 += __shfl_xor(v1, off);
            v2 += __shfl_xor(v2, off);
        }
        if (lane == 0) { w1[i] = v1; w2[i] = v2; }
        shwh[il * 65 + lane] = a;
    }
    __syncthreads();

    // transpose store: WhT[f][i0 + il], contiguous in il
#pragma unroll
    for (int it = 0; it < (OUTF * TILE1) / 256; ++it) {
        int idx = it * 256 + tid;
        int f = idx / TILE1, il = idx % TILE1;
        WhT[(size_t)f * NN + i0 + il] = f32_to_bf16(shwh[il * 65 + f]);
    }
}

// k2: per 64-row tile x column-split: stream adj, build P (masked exp) in
// bf16 A-fragments, MFMA against WhT B-fragments, accumulate Z in fp32.
__global__ __launch_bounds__(256) void k2_attn(
    const int* __restrict__ adj, const float* __restrict__ w1g,
    const float* __restrict__ w2g, const unsigned short* __restrict__ WhT,
    float* __restrict__ pacc, float* __restrict__ pz,
    int split, int cps)
{
    extern __shared__ float w2s[];
    const int tid = threadIdx.x;
    const int row_tile = blockIdx.x / split;
    const int s = blockIdx.x % split;
    const int jb = s * cps;

    for (int idx = tid; idx < cps; idx += 256) w2s[idx] = w2g[jb + idx];
    __syncthreads();

    const int wave = tid >> 6, lane = tid & 63;
    const int fl = lane & 15, g = lane >> 4;
    const int rw = row_tile * BM + wave * 16;
    const int lrow = rw + fl;
    const float w1r = w1g[lrow];

    f32x4 acc[4] = {};
    float zacc = 0.f;

    const int* aptr = adj + (size_t)lrow * NN + jb + g * 8;
    const unsigned short* bbase = WhT + (size_t)fl * NN + jb + g * 8;

    const int nsteps = cps / 32;
#pragma unroll 2
    for (int t = 0; t < nsteps; ++t) {
        const int4   av0 = *(const int4*)(aptr + 32 * t);
        const int4   av1 = *(const int4*)(aptr + 32 * t + 4);
        const float4 wv0 = *(const float4*)(w2s + 32 * t + g * 8);
        const float4 wv1 = *(const float4*)(w2s + 32 * t + g * 8 + 4);

        int   ai[8] = {av0.x, av0.y, av0.z, av0.w, av1.x, av1.y, av1.z, av1.w};
        float wv[8] = {wv0.x, wv0.y, wv0.z, wv0.w, wv1.x, wv1.y, wv1.z, wv1.w};
        union { bf16x8 v; unsigned short u[8]; } af;
#pragma unroll
        for (int e = 0; e < 8; ++e) {
            float sv = w1r + wv[e];
            float el = fmaxf(sv, 0.2f * sv);          // leaky_relu, slope 0.2
            float pe = (ai[e] > 0) ? __expf(el) : C0; // masked fill -> exp(9e-5)
            zacc += pe;
            af.u[e] = f32_to_bf16(pe);
        }
#pragma unroll
        for (int n = 0; n < 4; ++n) {
            bf16x8 bv = *(const bf16x8*)(bbase + (size_t)n * 16 * NN + 32 * t);
            acc[n] = __builtin_amdgcn_mfma_f32_16x16x32_bf16(af.v, bv, acc[n], 0, 0, 0);
        }
    }

    // Z: sum the 4 k-groups (lanes fl, fl+16, fl+32, fl+48)
    zacc += __shfl_xor(zacc, 32);
    zacc += __shfl_xor(zacc, 16);
    if (lane < 16) pz[(size_t)s * NN + rw + lane] = zacc;

    // D layout: row m = g*4 + r, col = n*16 + fl
#pragma unroll
    for (int n = 0; n < 4; ++n)
#pragma unroll
        for (int r = 0; r < 4; ++r) {
            int row = rw + g * 4 + r;
            pacc[((size_t)s * NN + row) * OUTF + n * 16 + fl] = acc[n][r];
        }
}

// k3: combine splits, divide by Z, add bias
__global__ __launch_bounds__(256) void k3_final(
    const float* __restrict__ pacc, const float* __restrict__ pz,
    const float* __restrict__ bias, float* __restrict__ out, int split)
{
    const int t = blockIdx.x * 256 + threadIdx.x;
    const int i = t >> 6, f = t & 63;
    float num = 0.f, z = 0.f;
    for (int s = 0; s < split; ++s) {
        num += pacc[(size_t)s * NN * OUTF + t];
        z   += pz[(size_t)s * NN + i];
    }
    out[t] = num / z + bias[f];
}

extern "C" void kernel_launch(void* const* d_in, const int* in_sizes, int n_in,
                              void* d_out, int out_size, void* d_ws, size_t ws_size,
                              hipStream_t stream)
{
    const float* x     = (const float*)d_in[0];
    const int*   adj   = (const int*)d_in[1];
    const float* W     = (const float*)d_in[2];
    const float* alpha = (const float*)d_in[3];
    const float* bias  = (const float*)d_in[4];
    float* out = (float*)d_out;

    char* ws = (char*)d_ws;
    size_t off = 0;
    unsigned short* WhT = (unsigned short*)(ws + off); off += (size_t)NN * OUTF * 2;
    float* w1 = (float*)(ws + off); off += (size_t)NN * 4;
    float* w2 = (float*)(ws + off); off += (size_t)NN * 4;

    int split = 8;
    while (split > 1) {
        size_t need = off + (size_t)split * NN * 4 + (size_t)split * NN * OUTF * 4;
        if (need <= ws_size) break;
        split >>= 1;
    }
    float* pz   = (float*)(ws + off); off += (size_t)split * NN * 4;
    float* pacc = (float*)(ws + off); off += (size_t)split * NN * OUTF * 4;
    const int cps = NN / split;

    k1_proj<<<NN / TILE1, 256, 0, stream>>>(x, W, alpha, WhT, w1, w2);
    k2_attn<<<(NN / BM) * split, 256, cps * 4, stream>>>(adj, w1, w2, WhT, pacc, pz, split, cps);
    k3_final<<<(NN * OUTF) / 256, 256, 0, stream>>>(pacc, pz, bias, out, split);
}

// Round 2
// 124.034 us; speedup vs baseline: 1.0647x; 1.0647x over previous
//
#include <hip/hip_runtime.h>
#include <hip/hip_bf16.h>
#include <math.h>

// GAT: out = softmax(mask(lrelu(w1 + w2^T), adj)) @ (x@W) + bias
// adj (268 MB int32) is the only O(N^2) input -> stream it once at HBM BW,
// build masked-exp2 P tiles in registers (logits pre-scaled by log2e),
// bf16 MFMA P@Wh + a 5th MFMA vs ones for Z, 16-way column split, reduce.

#define NN    8192
#define INF   256
#define OUTF  64
#define TILE1 16
#define BM    64
#define C0    1.0000900040501013f   // expf(9e-5)
#define LOG2E 1.4426950408889634f

typedef __bf16 bf16x8 __attribute__((ext_vector_type(8)));
typedef float  f32x4  __attribute__((ext_vector_type(4)));

#if __has_builtin(__builtin_amdgcn_exp2f)
#define EXP2(x) __builtin_amdgcn_exp2f(x)
#else
#define EXP2(x) exp2f(x)
#endif

// k1: Wh = x @ W; w1/w2 = (Wh@a1/a2)*log2e; WhT = bf16(Wh)^T  [64][8192]
__global__ __launch_bounds__(256) void k1_proj(
    const float* __restrict__ x, const float* __restrict__ W,
    const float* __restrict__ alpha,
    __bf16* __restrict__ WhT, float* __restrict__ w1, float* __restrict__ w2)
{
    __shared__ float xs[TILE1 * INF];    // 16 KB
    __shared__ float shwh[TILE1 * 65];
    const int tid = threadIdx.x;
    const int i0 = blockIdx.x * TILE1;

    const float4* xsrc = (const float4*)(x + (size_t)i0 * INF);
    float4* xdst = (float4*)xs;
#pragma unroll
    for (int it = 0; it < (TILE1 * INF / 4) / 256; ++it)
        xdst[tid + it * 256] = xsrc[tid + it * 256];
    __syncthreads();

    const int wave = tid >> 6, lane = tid & 63;
    const float a1 = alpha[lane], a2 = alpha[OUTF + lane];
    const int ilbase = wave * 4;

    float acc[4] = {};
#pragma unroll 4
    for (int k4 = 0; k4 < INF / 4; ++k4) {
        float wk0 = W[(4 * k4 + 0) * OUTF + lane];
        float wk1 = W[(4 * k4 + 1) * OUTF + lane];
        float wk2 = W[(4 * k4 + 2) * OUTF + lane];
        float wk3 = W[(4 * k4 + 3) * OUTF + lane];
#pragma unroll
        for (int rr = 0; rr < 4; ++rr) {
            float4 xv = *(const float4*)&xs[(ilbase + rr) * INF + 4 * k4];
            acc[rr] = fmaf(xv.x, wk0, acc[rr]);
            acc[rr] = fmaf(xv.y, wk1, acc[rr]);
            acc[rr] = fmaf(xv.z, wk2, acc[rr]);
            acc[rr] = fmaf(xv.w, wk3, acc[rr]);
        }
    }

#pragma unroll
    for (int rr = 0; rr < 4; ++rr) {
        const int il = ilbase + rr;
        const int i  = i0 + il;
        float a = acc[rr];
        float v1 = a * a1, v2 = a * a2;
#pragma unroll
        for (int off = 32; off > 0; off >>= 1) {
            v1 += __shfl_xor(v1, off);
            v2 += __shfl_xor(v2, off);
        }
        if (lane == 0) { w1[i] = v1 * LOG2E; w2[i] = v2 * LOG2E; }
        shwh[il * 65 + lane] = a;
    }
    __syncthreads();

#pragma unroll
    for (int it = 0; it < (OUTF * TILE1) / 256; ++it) {
        int idx = it * 256 + tid;
        int f = idx / TILE1, il = idx % TILE1;
        WhT[(size_t)f * NN + i0 + il] = (__bf16)shwh[il * 65 + f];
    }
}

// k2: stream adj, masked exp2 -> bf16 A-frags, 4 MFMA (P@Wh) + 1 MFMA (Z).
template <int CPS>
__global__ __launch_bounds__(256) void k2_attn(
    const int* __restrict__ adj, const float* __restrict__ w1g,
    const float* __restrict__ w2g, const __bf16* __restrict__ WhT,
    float* __restrict__ pacc, float* __restrict__ pz)
{
    constexpr int SPL = NN / CPS;
    __shared__ float w2s[CPS];
    const int tid = threadIdx.x;
    const int row_tile = blockIdx.x / SPL;
    const int s  = blockIdx.x % SPL;      // same s -> same XCD (bid % 8) -> B-slice L2-resident
    const int jb = s * CPS;

    for (int idx = tid; idx < CPS; idx += 256) w2s[idx] = w2g[jb + idx];
    __syncthreads();

    const int wave = tid >> 6, lane = tid & 63;
    const int fl = lane & 15, g = lane >> 4;
    const int rw = row_tile * BM + wave * 16;
    const float w1r = w1g[rw + fl];

    f32x4 acc0 = {}, acc1 = {}, acc2 = {}, acc3 = {}, accZ = {};
    bf16x8 ones;
#pragma unroll
    for (int e = 0; e < 8; ++e) ones[e] = (__bf16)1.0f;

    const int4*   ap  = (const int4*)(adj + (size_t)(rw + fl) * NN + jb) + 2 * g;
    const __bf16* bb  = WhT + (size_t)fl * NN + jb + 8 * g;
    const float4* wsf = (const float4*)w2s + 2 * g;

    constexpr int NSTEPS = CPS / 32;
#pragma unroll 4
    for (int t = 0; t < NSTEPS; ++t) {
        int4   av0 = ap[8 * t], av1 = ap[8 * t + 1];
        float4 wv0 = wsf[8 * t], wv1 = wsf[8 * t + 1];
        int   ai[8] = {av0.x, av0.y, av0.z, av0.w, av1.x, av1.y, av1.z, av1.w};
        float wv[8] = {wv0.x, wv0.y, wv0.z, wv0.w, wv1.x, wv1.y, wv1.z, wv1.w};
        bf16x8 pa;
#pragma unroll
        for (int e = 0; e < 8; ++e) {
            float sv = w1r + wv[e];
            float el = fmaxf(sv, 0.2f * sv);     // leaky_relu (log2-domain)
            float pe = EXP2(el);
            pe = (ai[e] > 0) ? pe : C0;
            pa[e] = (__bf16)pe;
        }
        acc0 = __builtin_amdgcn_mfma_f32_16x16x32_bf16(pa, *(const bf16x8*)(bb + (size_t)0 * 16 * NN + 32 * t), acc0, 0, 0, 0);
        acc1 = __builtin_amdgcn_mfma_f32_16x16x32_bf16(pa, *(const bf16x8*)(bb + (size_t)1 * 16 * NN + 32 * t), acc1, 0, 0, 0);
        acc2 = __builtin_amdgcn_mfma_f32_16x16x32_bf16(pa, *(const bf16x8*)(bb + (size_t)2 * 16 * NN + 32 * t), acc2, 0, 0, 0);
        acc3 = __builtin_amdgcn_mfma_f32_16x16x32_bf16(pa, *(const bf16x8*)(bb + (size_t)3 * 16 * NN + 32 * t), acc3, 0, 0, 0);
        accZ = __builtin_amdgcn_mfma_f32_16x16x32_bf16(pa, ones, accZ, 0, 0, 0);
    }

    // Z: D[m][n] all-cols-equal row sums; row m = g*4+r
    if (fl == 0) {
#pragma unroll
        for (int r = 0; r < 4; ++r)
            pz[(size_t)s * NN + rw + g * 4 + r] = accZ[r];
    }
    // numerator: row = rw + g*4 + r, col = n*16 + fl
    float* prow = pacc + ((size_t)s * NN + rw + g * 4) * OUTF + fl;
#pragma unroll
    for (int r = 0; r < 4; ++r) {
        prow[(size_t)r * OUTF +  0] = acc0[r];
        prow[(size_t)r * OUTF + 16] = acc1[r];
        prow[(size_t)r * OUTF + 32] = acc2[r];
        prow[(size_t)r * OUTF + 48] = acc3[r];
    }
}

// k3: combine splits, divide by Z, add bias
template <int SPL>
__global__ __launch_bounds__(256) void k3_final(
    const float* __restrict__ pacc, const float* __restrict__ pz,
    const float* __restrict__ bias, float* __restrict__ out)
{
    const int t = blockIdx.x * 256 + threadIdx.x;
    const int i = t >> 6, f = t & 63;
    float num = 0.f, z = 0.f;
#pragma unroll
    for (int s = 0; s < SPL; ++s) {
        num += pacc[(size_t)s * NN * OUTF + t];
        z   += pz[(size_t)s * NN + i];
    }
    out[t] = num / z + bias[f];
}

extern "C" void kernel_launch(void* const* d_in, const int* in_sizes, int n_in,
                              void* d_out, int out_size, void* d_ws, size_t ws_size,
                              hipStream_t stream)
{
    const float* x     = (const float*)d_in[0];
    const int*   adj   = (const int*)d_in[1];
    const float* W     = (const float*)d_in[2];
    const float* alpha = (const float*)d_in[3];
    const float* bias  = (const float*)d_in[4];
    float* out = (float*)d_out;

    char* ws = (char*)d_ws;
    size_t off = 0;
    __bf16* WhT = (__bf16*)(ws + off); off += (size_t)NN * OUTF * 2;
    float* w1 = (float*)(ws + off); off += (size_t)NN * 4;
    float* w2 = (float*)(ws + off); off += (size_t)NN * 4;

    const size_t need16 = off + (size_t)16 * NN * 4 + (size_t)16 * NN * OUTF * 4;
    const int split = (ws_size >= need16) ? 16 : 8;
    float* pz   = (float*)(ws + off); off += (size_t)split * NN * 4;
    float* pacc = (float*)(ws + off); off += (size_t)split * NN * OUTF * 4;

    k1_proj<<<NN / TILE1, 256, 0, stream>>>(x, W, alpha, WhT, w1, w2);
    if (split == 16) {
        k2_attn<NN / 16><<<(NN / BM) * 16, 256, 0, stream>>>(adj, w1, w2, WhT, pacc, pz);
        k3_final<16><<<(NN * OUTF) / 256, 256, 0, stream>>>(pacc, pz, bias, out);
    } else {
        k2_attn<NN / 8><<<(NN / BM) * 8, 256, 0, stream>>>(adj, w1, w2, WhT, pacc, pz);
        k3_final<8><<<(NN * OUTF) / 256, 256, 0, stream>>>(pacc, pz, bias, out);
    }
}

// Round 3
// 120.239 us; speedup vs baseline: 1.0983x; 1.0316x over previous
//
#include <hip/hip_runtime.h>
#include <hip/hip_bf16.h>
#include <math.h>

// GAT: out = softmax(mask(lrelu(w1 + w2^T), adj)) @ (x@W) + bias
// adj (268 MB int32) is the only O(N^2) input. k2 streams it with 1KB
// contiguous per-row bursts (DRAM-page friendly), converts to bf16 P in
// registers, stages P per-wave in swizzled LDS, MFMAs P@Wh (+ ones for Z).
// No barriers in k2's main loop: each wave uses only its own LDS strip.

#define NN    8192
#define INF   256
#define OUTF  64
#define TILE1 16
#define BM    64
#define SPL   8
#define CPS   (NN / SPL)    // 1024
#define KT    256           // cols per super-step (1KB int32 per row)
#define NSS   (CPS / KT)    // 4
#define C0    1.0000900040501013f   // expf(9e-5)
#define LOG2E 1.4426950408889634f

typedef __bf16 bf16x8 __attribute__((ext_vector_type(8)));
typedef __bf16 bf16x4 __attribute__((ext_vector_type(4)));
typedef float  f32x4  __attribute__((ext_vector_type(4)));
typedef int    i32x4  __attribute__((ext_vector_type(4)));

#if __has_builtin(__builtin_amdgcn_exp2f)
#define EXP2(x) __builtin_amdgcn_exp2f(x)
#else
#define EXP2(x) exp2f(x)
#endif

__device__ __forceinline__ __bf16 pcalc(int a, float sv) {
    float el = fmaxf(sv, 0.2f * sv);     // leaky_relu (log2-domain logits)
    float pe = EXP2(el);
    return (__bf16)(a > 0 ? pe : C0);
}

// k1: Wh = x @ W; w1/w2 = (Wh@a1/a2)*log2e; WhT = bf16(Wh)^T  [64][8192]
__global__ __launch_bounds__(256) void k1_proj(
    const float* __restrict__ x, const float* __restrict__ W,
    const float* __restrict__ alpha,
    __bf16* __restrict__ WhT, float* __restrict__ w1, float* __restrict__ w2)
{
    __shared__ float xs[TILE1 * INF];    // 16 KB
    __shared__ float shwh[TILE1 * 65];
    const int tid = threadIdx.x;
    const int i0 = blockIdx.x * TILE1;

    const float4* xsrc = (const float4*)(x + (size_t)i0 * INF);
    float4* xdst = (float4*)xs;
#pragma unroll
    for (int it = 0; it < (TILE1 * INF / 4) / 256; ++it)
        xdst[tid + it * 256] = xsrc[tid + it * 256];
    __syncthreads();

    const int wave = tid >> 6, lane = tid & 63;
    const float a1 = alpha[lane], a2 = alpha[OUTF + lane];
    const int ilbase = wave * 4;

    float acc[4] = {};
#pragma unroll 4
    for (int k4 = 0; k4 < INF / 4; ++k4) {
        float wk0 = W[(4 * k4 + 0) * OUTF + lane];
        float wk1 = W[(4 * k4 + 1) * OUTF + lane];
        float wk2 = W[(4 * k4 + 2) * OUTF + lane];
        float wk3 = W[(4 * k4 + 3) * OUTF + lane];
#pragma unroll
        for (int rr = 0; rr < 4; ++rr) {
            float4 xv = *(const float4*)&xs[(ilbase + rr) * INF + 4 * k4];
            acc[rr] = fmaf(xv.x, wk0, acc[rr]);
            acc[rr] = fmaf(xv.y, wk1, acc[rr]);
            acc[rr] = fmaf(xv.z, wk2, acc[rr]);
            acc[rr] = fmaf(xv.w, wk3, acc[rr]);
        }
    }

#pragma unroll
    for (int rr = 0; rr < 4; ++rr) {
        const int il = ilbase + rr;
        const int i  = i0 + il;
        float a = acc[rr];
        float v1 = a * a1, v2 = a * a2;
#pragma unroll
        for (int off = 32; off > 0; off >>= 1) {
            v1 += __shfl_xor(v1, off);
            v2 += __shfl_xor(v2, off);
        }
        if (lane == 0) { w1[i] = v1 * LOG2E; w2[i] = v2 * LOG2E; }
        shwh[il * 65 + lane] = a;
    }
    __syncthreads();

#pragma unroll
    for (int it = 0; it < (OUTF * TILE1) / 256; ++it) {
        int idx = it * 256 + tid;
        int f = idx / TILE1, il = idx % TILE1;
        WhT[(size_t)f * NN + i0 + il] = (__bf16)shwh[il * 65 + f];
    }
}

// k2: per wave: 16 rows. Super-step: 16x 1KB contiguous adj loads -> exp ->
// bf16 P into private swizzled LDS strip -> 8 MFMA k-steps (4 outs + Z).
__global__ __launch_bounds__(256) void k2_attn(
    const int* __restrict__ adj, const float* __restrict__ w1g,
    const float* __restrict__ w2g, const __bf16* __restrict__ WhT,
    float* __restrict__ pacc, float* __restrict__ pz)
{
    __shared__ __align__(16) char plds[4 * 16 * KT * 2];  // 32KB: 8KB/wave
    __shared__ float w2s[CPS];                            // 4KB
    __shared__ float w1s[BM];
    const int tid = threadIdx.x;
    const int s  = blockIdx.x & (SPL - 1);    // bid%8 -> XCD-aligned slices
    const int row_tile = blockIdx.x >> 3;
    const int jb = s * CPS;

    ((float4*)w2s)[tid] = ((const float4*)(w2g + jb))[tid];
    if (tid < BM) w1s[tid] = w1g[row_tile * BM + tid];
    __syncthreads();

    const int wave = tid >> 6, lane = tid & 63;
    const int fl = lane & 15, g = lane >> 4;
    const int rw0 = row_tile * BM + wave * 16;

    f32x4 acc0 = {}, acc1 = {}, acc2 = {}, acc3 = {}, accZ = {};
    bf16x8 ones;
#pragma unroll
    for (int e = 0; e < 8; ++e) ones[e] = (__bf16)1.0f;

    char* pb = plds + wave * (16 * KT * 2);
    const __bf16* bb = WhT + (size_t)fl * NN + jb;

    for (int ss = 0; ss < NSS; ++ss) {
        const int coff = ss * KT;
        const float4 wv = *(const float4*)(w2s + coff + 4 * lane);

        // 16 contiguous 1KB row-chunk loads (whole wave covers one row each)
        i32x4 av[16];
#pragma unroll
        for (int r = 0; r < 16; ++r)
            av[r] = __builtin_nontemporal_load(
                (const i32x4*)(adj + (size_t)(rw0 + r) * NN + jb + coff) + lane);

        // convert + swizzled LDS write (row r: byte ^= (r&7)<<4)
#pragma unroll
        for (int r = 0; r < 16; ++r) {
            const float w1r = w1s[wave * 16 + r];
            i32x4 a = av[r];
            bf16x4 pv;
            pv[0] = pcalc(a[0], w1r + wv.x);
            pv[1] = pcalc(a[1], w1r + wv.y);
            pv[2] = pcalc(a[2], w1r + wv.z);
            pv[3] = pcalc(a[3], w1r + wv.w);
            *(bf16x4*)(pb + r * (KT * 2) + ((lane * 8) ^ ((r & 7) << 4))) = pv;
        }

        // MFMA phase: A-frag from own LDS strip, B-frag from WhT (L1/L2)
#pragma unroll
        for (int t = 0; t < KT / 32; ++t) {
            bf16x8 af = *(const bf16x8*)(
                pb + fl * (KT * 2) + (((t << 6) + (g << 4)) ^ ((fl & 7) << 4)));
            const __bf16* bcol = bb + coff + 32 * t + 8 * g;
            acc0 = __builtin_amdgcn_mfma_f32_16x16x32_bf16(af, *(const bf16x8*)(bcol + (size_t)0 * 16 * NN), acc0, 0, 0, 0);
            acc1 = __builtin_amdgcn_mfma_f32_16x16x32_bf16(af, *(const bf16x8*)(bcol + (size_t)1 * 16 * NN), acc1, 0, 0, 0);
            acc2 = __builtin_amdgcn_mfma_f32_16x16x32_bf16(af, *(const bf16x8*)(bcol + (size_t)2 * 16 * NN), acc2, 0, 0, 0);
            acc3 = __builtin_amdgcn_mfma_f32_16x16x32_bf16(af, *(const bf16x8*)(bcol + (size_t)3 * 16 * NN), acc3, 0, 0, 0);
            accZ = __builtin_amdgcn_mfma_f32_16x16x32_bf16(af, ones, accZ, 0, 0, 0);
        }
    }

    // Z row sums (D row = g*4 + i, all cols equal)
    if (fl == 0) {
#pragma unroll
        for (int i = 0; i < 4; ++i)
            pz[(size_t)s * NN + rw0 + 4 * g + i] = accZ[i];
    }
    // numerator: row = rw0 + g*4 + i, col = n*16 + fl
    float* prow = pacc + ((size_t)s * NN + rw0 + 4 * g) * OUTF + fl;
#pragma unroll
    for (int i = 0; i < 4; ++i) {
        __builtin_nontemporal_store(acc0[i], prow + (size_t)i * OUTF + 0);
        __builtin_nontemporal_store(acc1[i], prow + (size_t)i * OUTF + 16);
        __builtin_nontemporal_store(acc2[i], prow + (size_t)i * OUTF + 32);
        __builtin_nontemporal_store(acc3[i], prow + (size_t)i * OUTF + 48);
    }
}

// k3: combine splits, divide by Z, add bias
__global__ __launch_bounds__(256) void k3_final(
    const float* __restrict__ pacc, const float* __restrict__ pz,
    const float* __restrict__ bias, float* __restrict__ out)
{
    const int t = blockIdx.x * 256 + threadIdx.x;
    const int i = t >> 6, f = t & 63;
    float num = 0.f, z = 0.f;
#pragma unroll
    for (int s = 0; s < SPL; ++s) {
        num += pacc[(size_t)s * NN * OUTF + t];
        z   += pz[(size_t)s * NN + i];
    }
    out[t] = num / z + bias[f];
}

extern "C" void kernel_launch(void* const* d_in, const int* in_sizes, int n_in,
                              void* d_out, int out_size, void* d_ws, size_t ws_size,
                              hipStream_t stream)
{
    const float* x     = (const float*)d_in[0];
    const int*   adj   = (const int*)d_in[1];
    const float* W     = (const float*)d_in[2];
    const float* alpha = (const float*)d_in[3];
    const float* bias  = (const float*)d_in[4];
    float* out = (float*)d_out;

    char* ws = (char*)d_ws;
    size_t off = 0;
    __bf16* WhT = (__bf16*)(ws + off); off += (size_t)NN * OUTF * 2;
    float* w1 = (float*)(ws + off); off += (size_t)NN * 4;
    float* w2 = (float*)(ws + off); off += (size_t)NN * 4;
    float* pz   = (float*)(ws + off); off += (size_t)SPL * NN * 4;
    float* pacc = (float*)(ws + off); off += (size_t)SPL * NN * OUTF * 4;

    k1_proj<<<NN / TILE1, 256, 0, stream>>>(x, W, alpha, WhT, w1, w2);
    k2_attn<<<(NN / BM) * SPL, 256, 0, stream>>>(adj, w1, w2, WhT, pacc, pz);
    k3_final<<<(NN * OUTF) / 256, 256, 0, stream>>>(pacc, pz, bias, out);
}